// Round 12
// baseline (813.699 us; speedup 1.0000x reference)
//
#include <hip/hip_runtime.h>
#include <hip/hip_fp16.h>

// GIN regression: pre-MLP -> 3x GINConv (BN folded) -> mean-pool -> head.
// Tier 1 (round-12): 3-level atomic-free CSR build -> per-(dst,chunk) rowptr2 + chunk-sorted
//   csr2. Conv = single kernel, z in registers, EXPLICIT loop over C chunks so all lanes /
//   waves / blocks sweep the same 2MB src window in lockstep (whole grid co-resident) ->
//   each XCD fetches each h line ~once per conv (round-11 drifted, 3x over-fetch).
// Tier 2: plain gather conv. Tier 3: round-1 scatter/update.

static constexpr int HF = 10;    // hidden features
static constexpr int HPH = 16;   // padded fp16 row stride in halfs (32 B)
static constexpr int FIN = 16;   // input features
static constexpr int BLK = 256;
static constexpr int UB = 8;     // tier-2 gather batch
static constexpr int SREP = 128; // stats replicas (x32 floats each)
static constexpr int BWB = 13;   // bucket window bits (8192 dsts/bucket)
static constexpr int SRB = 19;   // src bits in packed word (N must be <= 2^19)
static constexpr int EPB = 4096; // edges per partition block

static inline size_t alignup(size_t x) { return (x + 255) & ~(size_t)255; }

__device__ inline void unpack_add(uint4 a, uint a2, float* z) {
    float2 t;
    t = __half22float2(*reinterpret_cast<const __half2*>(&a.x)); z[0] += t.x; z[1] += t.y;
    t = __half22float2(*reinterpret_cast<const __half2*>(&a.y)); z[2] += t.x; z[3] += t.y;
    t = __half22float2(*reinterpret_cast<const __half2*>(&a.z)); z[4] += t.x; z[5] += t.y;
    t = __half22float2(*reinterpret_cast<const __half2*>(&a.w)); z[6] += t.x; z[7] += t.y;
    t = __half22float2(*reinterpret_cast<const __half2*>(&a2));  z[8] += t.x; z[9] += t.y;
}

__device__ inline void unpack_fma(uint4 a, uint a2, float w, float* z) {
    float2 t;
    t = __half22float2(*reinterpret_cast<const __half2*>(&a.x)); z[0] = fmaf(w, t.x, z[0]); z[1] = fmaf(w, t.y, z[1]);
    t = __half22float2(*reinterpret_cast<const __half2*>(&a.y)); z[2] = fmaf(w, t.x, z[2]); z[3] = fmaf(w, t.y, z[3]);
    t = __half22float2(*reinterpret_cast<const __half2*>(&a.z)); z[4] = fmaf(w, t.x, z[4]); z[5] = fmaf(w, t.y, z[5]);
    t = __half22float2(*reinterpret_cast<const __half2*>(&a.w)); z[6] = fmaf(w, t.x, z[6]); z[7] = fmaf(w, t.y, z[7]);
    t = __half22float2(*reinterpret_cast<const __half2*>(&a2));  z[8] = fmaf(w, t.x, z[8]); z[9] = fmaf(w, t.y, z[9]);
}

__device__ inline void store_row_f16(__half* row, const float* o) {
    __half2 p01 = __floats2half2_rn(o[0], o[1]);
    __half2 p23 = __floats2half2_rn(o[2], o[3]);
    __half2 p45 = __floats2half2_rn(o[4], o[5]);
    __half2 p67 = __floats2half2_rn(o[6], o[7]);
    __half2 p89 = __floats2half2_rn(o[8], o[9]);
    uint4 w;
    w.x = *reinterpret_cast<uint*>(&p01);
    w.y = *reinterpret_cast<uint*>(&p23);
    w.z = *reinterpret_cast<uint*>(&p45);
    w.w = *reinterpret_cast<uint*>(&p67);
    *reinterpret_cast<uint4*>(row) = w;
    *reinterpret_cast<uint*>(row + 8) = *reinterpret_cast<uint*>(&p89);
}

// Stats: wave shuffle -> LDS block reduce -> 1 atomic set/block into replica slot.
__device__ inline void stats_block_reduce(const float* o, float* stats) {
    __shared__ float sred[BLK / 64][32];
#pragma unroll
    for (int j = 0; j < HF; ++j) {
        float s = o[j];
        float q = o[j] * o[j];
#pragma unroll
        for (int off = 32; off > 0; off >>= 1) {
            s += __shfl_down(s, off);
            q += __shfl_down(q, off);
        }
        if ((threadIdx.x & 63) == 0) {
            sred[threadIdx.x >> 6][j] = s;
            sred[threadIdx.x >> 6][16 + j] = q;
        }
    }
    __syncthreads();
    int t = threadIdx.x;
    if (t < 32) {
        bool lo = (t < HF);
        bool hi = (t >= 16 && t < 16 + HF);
        if (lo || hi) {
            float v = sred[0][t] + sred[1][t] + sred[2][t] + sred[3][t];
            unsafeAtomicAdd(&stats[(blockIdx.x & (SREP - 1)) * 32 + t], v);
        }
    }
}

// ---------------- pre_mp ----------------
__global__ void pre_mp_f16_kernel(const float* __restrict__ x, const float* __restrict__ W,
                                  const float* __restrict__ b, __half* __restrict__ h, int N) {
    int i = blockIdx.x * blockDim.x + threadIdx.x;
    if (i >= N) return;
    const float4* xr = (const float4*)(x + (size_t)i * FIN);
    float xv[FIN];
    float4 x0 = xr[0], x1 = xr[1], x2 = xr[2], x3 = xr[3];
    xv[0]=x0.x; xv[1]=x0.y; xv[2]=x0.z; xv[3]=x0.w;
    xv[4]=x1.x; xv[5]=x1.y; xv[6]=x1.z; xv[7]=x1.w;
    xv[8]=x2.x; xv[9]=x2.y; xv[10]=x2.z; xv[11]=x2.w;
    xv[12]=x3.x; xv[13]=x3.y; xv[14]=x3.z; xv[15]=x3.w;
    float acc[HF];
#pragma unroll
    for (int j = 0; j < HF; ++j) acc[j] = b[j];
#pragma unroll
    for (int k = 0; k < FIN; ++k) {
#pragma unroll
        for (int j = 0; j < HF; ++j) acc[j] = fmaf(xv[k], W[k * HF + j], acc[j]);
    }
    store_row_f16(h + (size_t)i * HPH, acc);
}

__global__ void pre_mp_kernel(const float* __restrict__ x, const float* __restrict__ W,
                              const float* __restrict__ b, float* __restrict__ h, int N) {
    int i = blockIdx.x * blockDim.x + threadIdx.x;
    if (i >= N) return;
    const float4* xr = (const float4*)(x + (size_t)i * FIN);
    float xv[FIN];
    float4 x0 = xr[0], x1 = xr[1], x2 = xr[2], x3 = xr[3];
    xv[0]=x0.x; xv[1]=x0.y; xv[2]=x0.z; xv[3]=x0.w;
    xv[4]=x1.x; xv[5]=x1.y; xv[6]=x1.z; xv[7]=x1.w;
    xv[8]=x2.x; xv[9]=x2.y; xv[10]=x2.z; xv[11]=x2.w;
    xv[12]=x3.x; xv[13]=x3.y; xv[14]=x3.z; xv[15]=x3.w;
    float acc[HF];
#pragma unroll
    for (int j = 0; j < HF; ++j) acc[j] = b[j];
#pragma unroll
    for (int k = 0; k < FIN; ++k) {
#pragma unroll
        for (int j = 0; j < HF; ++j) acc[j] = fmaf(xv[k], W[k * HF + j], acc[j]);
    }
    float* hr = h + (size_t)i * HF;
#pragma unroll
    for (int j = 0; j < HF; ++j) hr[j] = acc[j];
}

// ---------------- scan machinery (tier-2) ----------------
__global__ void blocksum_kernel(const int* __restrict__ deg, int* __restrict__ bsum, int M) {
    int i = blockIdx.x * BLK + threadIdx.x;
    int v = (i < M) ? deg[i] : 0;
#pragma unroll
    for (int off = 32; off > 0; off >>= 1) v += __shfl_down(v, off);
    __shared__ int sm[BLK / 64];
    if ((threadIdx.x & 63) == 0) sm[threadIdx.x >> 6] = v;
    __syncthreads();
    if (threadIdx.x == 0) {
        int t = 0;
#pragma unroll
        for (int w = 0; w < BLK / 64; ++w) t += sm[w];
        bsum[blockIdx.x] = t;
    }
}

__global__ void scan_bsum_kernel(int* __restrict__ bs, int nb) {
    __shared__ int sm[1024];
    int running = 0;
    for (int base = 0; base < nb; base += 1024) {
        int i = base + (int)threadIdx.x;
        int v = (i < nb) ? bs[i] : 0;
        sm[threadIdx.x] = v;
        __syncthreads();
        for (int off = 1; off < 1024; off <<= 1) {
            int t = (threadIdx.x >= (unsigned)off) ? sm[threadIdx.x - off] : 0;
            __syncthreads();
            sm[threadIdx.x] += t;
            __syncthreads();
        }
        int incl = sm[threadIdx.x];
        if (i < nb) bs[i] = running + incl - v;  // exclusive
        int chunk_total = sm[1023];
        __syncthreads();
        running += chunk_total;
    }
}

__global__ void rowptr_kernel(const int* __restrict__ deg, const int* __restrict__ bsum,
                              int* __restrict__ rowptr, int* cursor, int M) {
    int i = blockIdx.x * BLK + threadIdx.x;
    int v = (i < M) ? deg[i] : 0;
    __shared__ int sm[BLK];
    sm[threadIdx.x] = v;
    __syncthreads();
    for (int off = 1; off < BLK; off <<= 1) {
        int t = (threadIdx.x >= (unsigned)off) ? sm[threadIdx.x - off] : 0;
        __syncthreads();
        sm[threadIdx.x] += t;
        __syncthreads();
    }
    int excl = sm[threadIdx.x] - v + bsum[blockIdx.x];
    if (i < M) {
        rowptr[i] = excl;
        cursor[i] = excl;
    }
}

// ---------------- atomic-free 3-level CSR build (tier-1) ----------------
__global__ void bucket_hist_kernel(const int* __restrict__ dst, int* __restrict__ bcount,
                                   int E, int B) {
    __shared__ int lcount[64];
    if (threadIdx.x < B) lcount[threadIdx.x] = 0;
    __syncthreads();
    int start = blockIdx.x * EPB;
    int end = min(start + EPB, E);
    for (int e = start + threadIdx.x; e < end; e += BLK)
        atomicAdd(&lcount[dst[e] >> BWB], 1);
    __syncthreads();
    if (threadIdx.x < B && lcount[threadIdx.x] > 0)
        atomicAdd(&bcount[threadIdx.x], lcount[threadIdx.x]);
}

__global__ void bucket_scan_kernel(const int* __restrict__ bcount, int* __restrict__ bbase,
                                   int* __restrict__ bcursor, int B) {
    if (threadIdx.x == 0) {
        int run = 0;
        for (int b = 0; b < B; ++b) {
            bbase[b] = run;
            bcursor[b] = run;
            run += bcount[b];
        }
        bbase[B] = run;
    }
}

// L1: partition into buckets; packed = (dst_low << SRB) | src
__global__ void partition_kernel(const int* __restrict__ src, const int* __restrict__ dst,
                                 int* __restrict__ bcursor, uint* __restrict__ packed,
                                 int E, int B) {
    __shared__ int lcount[64], lbase[64], lcur[64];
    int start = blockIdx.x * EPB;
    int end = min(start + EPB, E);
    if (threadIdx.x < B) lcount[threadIdx.x] = 0;
    __syncthreads();
    for (int e = start + threadIdx.x; e < end; e += BLK)
        atomicAdd(&lcount[dst[e] >> BWB], 1);
    __syncthreads();
    if (threadIdx.x < B) {
        lbase[threadIdx.x] = (lcount[threadIdx.x] > 0)
                           ? atomicAdd(&bcursor[threadIdx.x], lcount[threadIdx.x]) : 0;
        lcur[threadIdx.x] = 0;
    }
    __syncthreads();
    for (int e = start + threadIdx.x; e < end; e += BLK) {
        int d = dst[e];
        int b = d >> BWB;
        int p = lbase[b] + atomicAdd(&lcur[b], 1);
        packed[p] = ((uint)(d & ((1 << BWB) - 1)) << SRB) | (uint)src[e];
    }
}

__device__ inline int find_bucket(const int* sbase, int B, int p) {
    int lo = 0, hi = B;
    while (hi - lo > 1) {
        int mid = (lo + hi) >> 1;
        if (p >= sbase[mid]) lo = mid; else hi = mid;
    }
    return lo;
}

// L2 hist: group = (bucket<<6) | (dst_low>>7)
__global__ void l2_hist_kernel(const uint* __restrict__ packed1, const int* __restrict__ bbase,
                               int* __restrict__ gcount, int E, int B) {
    __shared__ int sbase[65];
    __shared__ int lcount[128];
    __shared__ int g0s;
    if (threadIdx.x <= B) sbase[threadIdx.x] = bbase[threadIdx.x];
    if (threadIdx.x < 128) lcount[threadIdx.x] = 0;
    __syncthreads();
    int start = blockIdx.x * EPB;
    int end = min(start + EPB, E);
    if (start >= E) return;
    if (threadIdx.x == 0) g0s = find_bucket(sbase, B, start) << 6;
    __syncthreads();
    int g0 = g0s;
    for (int p = start + threadIdx.x; p < end; p += BLK) {
        uint v = packed1[p];
        int b = find_bucket(sbase, B, p);
        int g = (b << 6) | (((int)(v >> SRB)) >> 7);
        atomicAdd(&lcount[g - g0], 1);
    }
    __syncthreads();
    if (threadIdx.x < 128 && lcount[threadIdx.x] > 0)
        atomicAdd(&gcount[g0 + threadIdx.x], lcount[threadIdx.x]);
}

__global__ void l2_scan_kernel(const int* __restrict__ gcount, int* __restrict__ gbase,
                               int* __restrict__ gcursor, int NG) {
    __shared__ int sm[1024];
    int running = 0;
    for (int b0 = 0; b0 < NG; b0 += 1024) {
        int i = b0 + (int)threadIdx.x;
        int v = (i < NG) ? gcount[i] : 0;
        sm[threadIdx.x] = v;
        __syncthreads();
        for (int off = 1; off < 1024; off <<= 1) {
            int t = (threadIdx.x >= (unsigned)off) ? sm[threadIdx.x - off] : 0;
            __syncthreads();
            sm[threadIdx.x] += t;
            __syncthreads();
        }
        int incl = sm[threadIdx.x];
        if (i < NG) { gbase[i] = running + incl - v; gcursor[i] = running + incl - v; }
        int tot = sm[1023];
        __syncthreads();
        running += tot;
    }
    if (threadIdx.x == 0) gbase[NG] = running;
}

// L2 place: per-block partition into groups (single-XCD output regions)
__global__ void l2_place_kernel(const uint* __restrict__ packed1, const int* __restrict__ bbase,
                                int* __restrict__ gcursor, uint* __restrict__ packed2,
                                int E, int B) {
    __shared__ int sbase[65];
    __shared__ int lcount[128], lbase[128], lcur[128];
    __shared__ int g0s;
    if (threadIdx.x <= B) sbase[threadIdx.x] = bbase[threadIdx.x];
    if (threadIdx.x < 128) lcount[threadIdx.x] = 0;
    __syncthreads();
    int start = blockIdx.x * EPB;
    int end = min(start + EPB, E);
    if (start >= E) return;
    if (threadIdx.x == 0) g0s = find_bucket(sbase, B, start) << 6;
    __syncthreads();
    int g0 = g0s;
    for (int p = start + threadIdx.x; p < end; p += BLK) {
        uint v = packed1[p];
        int b = find_bucket(sbase, B, p);
        int bin = ((b << 6) | (((int)(v >> SRB)) >> 7)) - g0;
        atomicAdd(&lcount[bin], 1);
    }
    __syncthreads();
    if (threadIdx.x < 128) {
        lbase[threadIdx.x] = (lcount[threadIdx.x] > 0)
                           ? atomicAdd(&gcursor[g0 + threadIdx.x], lcount[threadIdx.x]) : 0;
        lcur[threadIdx.x] = 0;
    }
    __syncthreads();
    for (int p = start + threadIdx.x; p < end; p += BLK) {
        uint v = packed1[p];
        int b = find_bucket(sbase, B, p);
        int bin = ((b << 6) | (((int)(v >> SRB)) >> 7)) - g0;
        packed2[lbase[bin] + atomicAdd(&lcur[bin], 1)] = v;
    }
}

// L3: one block per group (~2K edges, 128 dsts). LDS sort by (dst&127)*C + chunk;
// plain stores of csr2 + FULL per-(dst,chunk) rowptr2 (block-exclusive regions).
__global__ void l3_sort_kernel(const uint* __restrict__ packed2, const int* __restrict__ gbase,
                               int* __restrict__ csr2, int* __restrict__ rowptr2,
                               int N, int C, int cbits, int E) {
    __shared__ int cnt[1024];
    __shared__ int bas[1024];
    __shared__ int tsum[256];
    int g = blockIdx.x;
    int start = gbase[g], end = gbase[g + 1];
    int dstbase = g << 7;
    int nb = 128 * C;
    for (int t = threadIdx.x; t < 1024; t += BLK) cnt[t] = 0;
    __syncthreads();
    for (int p = start + (int)threadIdx.x; p < end; p += BLK) {
        uint v = packed2[p];
        int s = (int)(v & ((1u << SRB) - 1));
        int dl7 = ((int)(v >> SRB)) & 127;
        atomicAdd(&cnt[dl7 * C + (s >> cbits)], 1);
    }
    __syncthreads();
    int tid = threadIdx.x;
    int c0 = cnt[4 * tid], c1 = cnt[4 * tid + 1], c2 = cnt[4 * tid + 2], c3 = cnt[4 * tid + 3];
    int mysum = c0 + c1 + c2 + c3;
    tsum[tid] = mysum;
    __syncthreads();
    for (int off = 1; off < 256; off <<= 1) {
        int t2 = (tid >= off) ? tsum[tid - off] : 0;
        __syncthreads();
        tsum[tid] += t2;
        __syncthreads();
    }
    int excl = tsum[tid] - mysum;
    bas[4 * tid] = excl;
    bas[4 * tid + 1] = excl + c0;
    bas[4 * tid + 2] = excl + c0 + c1;
    bas[4 * tid + 3] = excl + c0 + c1 + c2;
    __syncthreads();
    // full rowptr2: slot for (dst, c) = dst*C + c = g*128*C + t
    size_t slotbase = (size_t)g * nb;
    for (int t = threadIdx.x; t < nb; t += BLK) {
        int dstn = dstbase + t / C;
        if (dstn < N) rowptr2[slotbase + t] = start + bas[t];
    }
    // reuse cnt as cursor
    for (int t = threadIdx.x; t < 1024; t += BLK) cnt[t] = 0;
    __syncthreads();
    for (int p = start + (int)threadIdx.x; p < end; p += BLK) {
        uint v = packed2[p];
        int s = (int)(v & ((1u << SRB) - 1));
        int dl7 = ((int)(v >> SRB)) & 127;
        int key = dl7 * C + (s >> cbits);
        int pos = start + bas[key] + atomicAdd(&cnt[key], 1);
        csr2[pos] = s;
    }
}

// tier-2 CSR build
__global__ void hist_kernel(const int* __restrict__ idx, int* __restrict__ deg, int E) {
    int e = blockIdx.x * blockDim.x + threadIdx.x;
    if (e >= E) return;
    atomicAdd(&deg[idx[e]], 1);
}

__global__ void fill_kernel(const int* __restrict__ src, const int* __restrict__ dst,
                            int* __restrict__ cursor, int* __restrict__ csr, int E) {
    int e = blockIdx.x * blockDim.x + threadIdx.x;
    if (e >= E) return;
    int pos = atomicAdd(&cursor[dst[e]], 1);
    csr[pos] = src[e];
}

// ---------------- tier-1 chunk-looped conv (z in registers, lockstep window sweep) -------
template <bool BN, bool STATS, bool POOL>
__global__ void __launch_bounds__(BLK) conv_chunked_kernel(
        const __half* __restrict__ hin, const int* __restrict__ rp2,
        const int* __restrict__ csr, const float* __restrict__ ss,
        const float* __restrict__ W1, const float* __restrict__ b1,
        const float* __restrict__ W2, const float* __restrict__ b2,
        __half* __restrict__ hout, int N, int C, int E, float* stats,
        const int* __restrict__ batch, float* pool, float* cnt) {
    int i = blockIdx.x * blockDim.x + threadIdx.x;
    bool act = i < N;
    float o[HF];
    int g = 0x7fffffff;
    if (act) {
        float z[HF];
#pragma unroll
        for (int j = 0; j < HF; ++j) z[j] = 0.0f;
        {
            const __half* hp = hin + (size_t)i * HPH;
            uint4 r = *reinterpret_cast<const uint4*>(hp);
            uint r2 = *reinterpret_cast<const uint*>(hp + 8);
            unpack_add(r, r2, z);
        }
        size_t m0 = (size_t)i * C;
        size_t mend = (size_t)N * C;
        int b = rp2[m0];
        int row0 = b;
        for (int c = 0; c < C; ++c) {
            size_t mn = m0 + c + 1;
            int e2 = (mn < mend) ? rp2[mn] : E;
            int k = b;
            for (; k + 2 <= e2; k += 2) {
                int s0 = csr[k], s1 = csr[k + 1];
                const __half* p0 = hin + (size_t)s0 * HPH;
                const __half* p1 = hin + (size_t)s1 * HPH;
                uint4 a0 = *reinterpret_cast<const uint4*>(p0);
                uint  b0 = *reinterpret_cast<const uint*>(p0 + 8);
                uint4 a1 = *reinterpret_cast<const uint4*>(p1);
                uint  b1v = *reinterpret_cast<const uint*>(p1 + 8);
                unpack_add(a0, b0, z);
                unpack_add(a1, b1v, z);
            }
            if (k < e2) {
                int s0 = csr[k];
                const __half* p0 = hin + (size_t)s0 * HPH;
                uint4 a0 = *reinterpret_cast<const uint4*>(p0);
                uint  b0 = *reinterpret_cast<const uint*>(p0 + 8);
                unpack_add(a0, b0, z);
            }
            b = e2;
        }
        int d = b - row0;
        if (BN) {
            float dp1 = (float)(d + 1);
#pragma unroll
            for (int j = 0; j < HF; ++j) z[j] = fmaf(z[j], ss[j], dp1 * ss[HF + j]);
        }
        float t[HF];
#pragma unroll
        for (int j = 0; j < HF; ++j) {
            float a = b1[j];
#pragma unroll
            for (int k2 = 0; k2 < HF; ++k2) a = fmaf(z[k2], W1[k2 * HF + j], a);
            t[j] = fmaxf(a, 0.0f);
        }
#pragma unroll
        for (int j = 0; j < HF; ++j) {
            float a = b2[j];
#pragma unroll
            for (int k2 = 0; k2 < HF; ++k2) a = fmaf(t[k2], W2[k2 * HF + j], a);
            o[j] = a;
        }
        if (!POOL) {
            store_row_f16(hout + (size_t)i * HPH, o);
        } else {
            g = batch[i];
        }
    } else {
#pragma unroll
        for (int j = 0; j < HF; ++j) o[j] = 0.0f;
    }
    if (STATS) stats_block_reduce(o, stats);
    if (POOL) {
        int lane = threadIdx.x & 63;
        float c1 = act ? 1.0f : 0.0f;
#pragma unroll
        for (int off = 1; off < 64; off <<= 1) {
            int gu = __shfl_up(g, off);
            float cu = __shfl_up(c1, off);
            bool take = (lane >= off) && (gu == g);
            if (take) c1 += cu;
#pragma unroll
            for (int j = 0; j < HF; ++j) {
                float vu = __shfl_up(o[j], off);
                if (take) o[j] += vu;
            }
        }
        int gn = __shfl_down(g, 1);
        bool last = (lane == 63) || (gn != g);
        if (act && last) {
#pragma unroll
            for (int j = 0; j < HF; ++j) unsafeAtomicAdd(&pool[(size_t)g * HF + j], o[j]);
            unsafeAtomicAdd(&cnt[g], c1);
        }
    }
}

// ---------------- tier-2 conv ----------------
template <bool BN, bool STATS, bool POOL>
__global__ void __launch_bounds__(BLK) conv_kernel(
                            const __half* __restrict__ hin,
                            const int* __restrict__ rowptr, const int* __restrict__ deg,
                            const int* __restrict__ csr, const float* __restrict__ ss,
                            const float* __restrict__ W1, const float* __restrict__ b1,
                            const float* __restrict__ W2, const float* __restrict__ b2,
                            __half* __restrict__ hout, int N, float* stats,
                            const int* __restrict__ batch, float* pool, float* cnt) {
    int i = blockIdx.x * blockDim.x + threadIdx.x;
    bool act = i < N;
    float o[HF];
    int g = 0x7fffffff;
    if (act) {
        float z[HF];
#pragma unroll
        for (int j = 0; j < HF; ++j) z[j] = 0.0f;
        {
            const __half* hp = hin + (size_t)i * HPH;
            uint4 r = *reinterpret_cast<const uint4*>(hp);
            uint r2 = *reinterpret_cast<const uint*>(hp + 8);
            unpack_add(r, r2, z);
        }
        int base = rowptr[i];
        int d = deg[i];
        for (int k0 = 0; k0 < d; k0 += UB) {
            int s[UB];
            float w[UB];
#pragma unroll
            for (int u = 0; u < UB; ++u) {
                int kk = k0 + u;
                int kc = kk < d ? kk : d - 1;
                s[u] = csr[base + kc];
                w[u] = kk < d ? 1.0f : 0.0f;
            }
            uint4 a[UB];
            uint a2[UB];
#pragma unroll
            for (int u = 0; u < UB; ++u) {
                const __half* sp = hin + (size_t)s[u] * HPH;
                a[u]  = *reinterpret_cast<const uint4*>(sp);
                a2[u] = *reinterpret_cast<const uint*>(sp + 8);
            }
#pragma unroll
            for (int u = 0; u < UB; ++u) unpack_fma(a[u], a2[u], w[u], z);
        }
        if (BN) {
            float dp1 = (float)(d + 1);
#pragma unroll
            for (int j = 0; j < HF; ++j) z[j] = fmaf(z[j], ss[j], dp1 * ss[HF + j]);
        }
        float t[HF];
#pragma unroll
        for (int j = 0; j < HF; ++j) {
            float a = b1[j];
#pragma unroll
            for (int k = 0; k < HF; ++k) a = fmaf(z[k], W1[k * HF + j], a);
            t[j] = fmaxf(a, 0.0f);
        }
#pragma unroll
        for (int j = 0; j < HF; ++j) {
            float a = b2[j];
#pragma unroll
            for (int k = 0; k < HF; ++k) a = fmaf(t[k], W2[k * HF + j], a);
            o[j] = a;
        }
        if (!POOL) {
            store_row_f16(hout + (size_t)i * HPH, o);
        } else {
            g = batch[i];
        }
    } else {
#pragma unroll
        for (int j = 0; j < HF; ++j) o[j] = 0.0f;
    }
    if (STATS) stats_block_reduce(o, stats);
    if (POOL) {
        int lane = threadIdx.x & 63;
        float c1 = act ? 1.0f : 0.0f;
#pragma unroll
        for (int off = 1; off < 64; off <<= 1) {
            int gu = __shfl_up(g, off);
            float cu = __shfl_up(c1, off);
            bool take = (lane >= off) && (gu == g);
            if (take) c1 += cu;
#pragma unroll
            for (int j = 0; j < HF; ++j) {
                float vu = __shfl_up(o[j], off);
                if (take) o[j] += vu;
            }
        }
        int gn = __shfl_down(g, 1);
        bool last = (lane == 63) || (gn != g);
        if (act && last) {
#pragma unroll
            for (int j = 0; j < HF; ++j) unsafeAtomicAdd(&pool[(size_t)g * HF + j], o[j]);
            unsafeAtomicAdd(&cnt[g], c1);
        }
    }
}

// ---------------- BN finalize (sums R replica slots) / head ----------------
__global__ void bn_finalize_kernel(const float* __restrict__ stats,
                                   const float* __restrict__ gamma,
                                   const float* __restrict__ beta,
                                   float* __restrict__ ss, float invN, int R) {
    int j = threadIdx.x;
    if (j >= HF) return;
    float sm = 0.0f, sq = 0.0f;
    for (int r = 0; r < R; ++r) {
        sm += stats[r * 32 + j];
        sq += stats[r * 32 + 16 + j];
    }
    float mean = sm * invN;
    float var = sq * invN - mean * mean;
    float sc = gamma[j] * rsqrtf(var + 1e-5f);
    ss[j] = sc;
    ss[HF + j] = beta[j] - mean * sc;
}

__global__ void head_kernel(const float* __restrict__ pool, const float* __restrict__ cnt,
                            const float* __restrict__ W1, const float* __restrict__ b1,
                            const float* __restrict__ W2, const float* __restrict__ b2,
                            float* __restrict__ out, int G) {
    int g = blockIdx.x * blockDim.x + threadIdx.x;
    if (g >= G) return;
    float inv = 1.0f / fmaxf(cnt[g], 1.0f);
    float p[HF];
    const float* pr = pool + (size_t)g * HF;
#pragma unroll
    for (int j = 0; j < HF; ++j) p[j] = pr[j] * inv;
    float acc = b2[0];
#pragma unroll
    for (int j = 0; j < HF; ++j) {
        float a = b1[j];
#pragma unroll
        for (int k = 0; k < HF; ++k) a = fmaf(p[k], W1[k * HF + j], a);
        acc = fmaf(fmaxf(a, 0.0f), W2[j], acc);
    }
    out[g] = acc;
}

// ================= tier-3 (round-1, stats layout [j],[16+j], R=1) ========
template <bool BN>
__global__ void scatter_kernel(const int* __restrict__ src, const int* __restrict__ dst,
                               const float* __restrict__ h, const float* __restrict__ ss,
                               float* agg, int E) {
    int e = blockIdx.x * blockDim.x + threadIdx.x;
    if (e >= E) return;
    int s = src[e];
    int d = dst[e];
    const float* hr = h + (size_t)s * HF;
    float* ar = agg + (size_t)d * HF;
#pragma unroll
    for (int j = 0; j < HF; ++j) {
        float v = hr[j];
        if (BN) v = fmaf(v, ss[j], ss[HF + j]);
        unsafeAtomicAdd(&ar[j], v);
    }
}

template <bool BN, bool STATS>
__global__ void update_kernel(const float* __restrict__ h, const float* agg,
                              const float* __restrict__ ss,
                              const float* __restrict__ W1, const float* __restrict__ b1,
                              const float* __restrict__ W2, const float* __restrict__ b2,
                              float* out, int N, float* stats) {
    int i = blockIdx.x * blockDim.x + threadIdx.x;
    float o[HF];
    bool act = (i < N);
    if (act) {
        float z[HF];
        const float* hr = h + (size_t)i * HF;
        const float* ar = agg + (size_t)i * HF;
#pragma unroll
        for (int j = 0; j < HF; ++j) {
            float v = hr[j];
            if (BN) v = fmaf(v, ss[j], ss[HF + j]);
            z[j] = v + ar[j];
        }
        float t[HF];
#pragma unroll
        for (int j = 0; j < HF; ++j) {
            float a = b1[j];
#pragma unroll
            for (int k = 0; k < HF; ++k) a = fmaf(z[k], W1[k * HF + j], a);
            t[j] = fmaxf(a, 0.0f);
        }
        float* orow = out + (size_t)i * HF;
#pragma unroll
        for (int j = 0; j < HF; ++j) {
            float a = b2[j];
#pragma unroll
            for (int k = 0; k < HF; ++k) a = fmaf(t[k], W2[k * HF + j], a);
            o[j] = a;
            orow[j] = a;
        }
    } else {
#pragma unroll
        for (int j = 0; j < HF; ++j) o[j] = 0.0f;
    }
    if (STATS) {
#pragma unroll
        for (int j = 0; j < HF; ++j) {
            float s = o[j];
            float q = o[j] * o[j];
#pragma unroll
            for (int off = 32; off > 0; off >>= 1) {
                s += __shfl_down(s, off);
                q += __shfl_down(q, off);
            }
            if ((threadIdx.x & 63) == 0) {
                unsafeAtomicAdd(&stats[j], s);
                unsafeAtomicAdd(&stats[16 + j], q);
            }
        }
    }
}

__global__ void pool_atomic_kernel(const float* __restrict__ h, const int* __restrict__ batch,
                                   float* pool, float* cnt, int N) {
    int i = blockIdx.x * blockDim.x + threadIdx.x;
    if (i >= N) return;
    int g = batch[i];
    const float* hr = h + (size_t)i * HF;
    float* pr = pool + (size_t)g * HF;
#pragma unroll
    for (int j = 0; j < HF; ++j) unsafeAtomicAdd(&pr[j], hr[j]);
    unsafeAtomicAdd(&cnt[g], 1.0f);
}

extern "C" void kernel_launch(void* const* d_in, const int* in_sizes, int n_in,
                              void* d_out, int out_size, void* d_ws, size_t ws_size,
                              hipStream_t stream) {
    const float* x      = (const float*)d_in[0];
    const int*   ei     = (const int*)d_in[1];
    const int*   batch  = (const int*)d_in[2];
    const float* preW   = (const float*)d_in[3];
    const float* preb   = (const float*)d_in[4];
    const float* convW1 = (const float*)d_in[5];
    const float* convb1 = (const float*)d_in[6];
    const float* convW2 = (const float*)d_in[7];
    const float* convb2 = (const float*)d_in[8];
    const float* gamma  = (const float*)d_in[9];
    const float* beta   = (const float*)d_in[10];
    const float* postW1 = (const float*)d_in[11];
    const float* postb1 = (const float*)d_in[12];
    const float* postW2 = (const float*)d_in[13];
    const float* postb2 = (const float*)d_in[14];

    const int N = in_sizes[0] / FIN;
    const int E = in_sizes[1] / 2;
    const int G = out_size;
    const int* src = ei;
    const int* dst = ei + E;

    const int gN = (N + BLK - 1) / BLK;
    const int gE = (E + BLK - 1) / BLK;
    const int gG = (G + BLK - 1) / BLK;
    const int gP = (E + EPB - 1) / EPB;
    const float invN = 1.0f / (float)N;
    char* base = (char*)d_ws;

    const size_t statsFloats = (size_t)SREP * 32;
    const size_t smallFloats = 2 * statsFloats + 64 + 256 + (size_t)G * (HF + 1);

    // ---- tier-1 layout ----
    const int cbits = 16;
    const int C = (N + (1 << cbits) - 1) >> cbits;
    const int B = (N + (1 << BWB) - 1) >> BWB;
    const int NG = B * 64;
    const size_t M = (size_t)N * C;
    size_t ebytes = alignup((size_t)E * 4);

    size_t off1 = 0;
    auto take1 = [&](size_t bytes) { size_t o = off1; off1 += alignup(bytes); return o; };
    size_t pk1_o  = take1(ebytes);                // packed1, then csr2 (aliased)
    size_t pk2_o  = take1(ebytes);                // packed2
    size_t h0_o1  = take1((size_t)N * HPH * 2);
    size_t h1_o1  = take1((size_t)N * HPH * 2);
    size_t rp2_o  = take1((M + 8) * 4);           // per-(dst,chunk) rowptr2
    size_t gg_o   = take1((size_t)(3 * NG + 8) * 4);   // gcount | gbase(NG+1) | gcursor
    size_t sm_o1  = take1(smallFloats * 4);

    // ---- tier-2 layout ----
    size_t off2 = 0;
    auto take2 = [&](size_t bytes) { size_t o = off2; off2 += alignup(bytes); return o; };
    size_t csr_o2 = take2((size_t)E * 4);
    size_t h0_o2  = take2((size_t)N * HPH * 2);
    size_t h1_o2  = take2((size_t)N * HPH * 2);
    size_t deg_o2 = take2((size_t)N * 4);
    size_t row_o2 = take2((size_t)N * 4);
    size_t cur_o2 = take2((size_t)N * 4);
    size_t bs_o2  = take2((size_t)gN * 4);
    size_t sm_o2  = take2(smallFloats * 4);

    bool tier1_ok = (off1 <= ws_size) && (C >= 2) && (C <= 8) && (B <= 64) &&
                    (N <= (1 << SRB));

    if (tier1_ok) {
        // =================== tier 1 ===================
        int*    csr2   = (int*)(base + pk1_o);           // aliases packed1
        uint*   packed1= (uint*)(base + pk1_o);
        uint*   packed2= (uint*)(base + pk2_o);
        __half* h0     = (__half*)(base + h0_o1);
        __half* h1     = (__half*)(base + h1_o1);
        int*    rp2    = (int*)(base + rp2_o);
        int*    gcount = (int*)(base + gg_o);
        int*    gbase  = gcount + NG;                    // NG+1
        int*    gcursor= gbase + NG + 4;
        float*  small  = (float*)(base + sm_o1);
        float* stats0 = small;
        float* stats1 = small + statsFloats;
        float* ss0    = small + 2 * statsFloats;
        float* ss1    = ss0 + 32;
        int*   bcount = (int*)(ss1 + 32);        // 64
        int*   bbase  = bcount + 64;             // 65
        int*   bcursor= bbase + 66;              // 64
        float* pool   = (float*)(bcursor + 64 + 2);
        float* cnt    = pool + (size_t)G * HF;

        pre_mp_f16_kernel<<<gN, BLK, 0, stream>>>(x, preW, preb, h0, N);

        hipMemsetAsync(stats0, 0, 2 * statsFloats * 4, stream);
        hipMemsetAsync(bcount, 0, 64 * 4, stream);
        hipMemsetAsync(gcount, 0, (size_t)NG * 4, stream);
        hipMemsetAsync(pool, 0, (size_t)G * (HF + 1) * 4, stream);

        // atomic-free 3-level CSR build (per-(dst,chunk) rowptr2 + chunk-sorted csr2)
        bucket_hist_kernel<<<gP, BLK, 0, stream>>>(dst, bcount, E, B);
        bucket_scan_kernel<<<1, 64, 0, stream>>>(bcount, bbase, bcursor, B);
        partition_kernel<<<gP, BLK, 0, stream>>>(src, dst, bcursor, packed1, E, B);
        l2_hist_kernel<<<gP, BLK, 0, stream>>>(packed1, bbase, gcount, E, B);
        l2_scan_kernel<<<1, 1024, 0, stream>>>(gcount, gbase, gcursor, NG);
        l2_place_kernel<<<gP, BLK, 0, stream>>>(packed1, bbase, gcursor, packed2, E, B);
        l3_sort_kernel<<<NG, BLK, 0, stream>>>(packed2, gbase, csr2, rp2, N, C, cbits, E);
        // packed1 consumed; csr2 occupies its region. packed2 dead after l3.

        // layer 0: h0 -> h1, stats0
        conv_chunked_kernel<false, true, false><<<gN, BLK, 0, stream>>>(h0, rp2, csr2,
            nullptr, convW1 + 0 * HF * HF, convb1 + 0 * HF, convW2 + 0 * HF * HF,
            convb2 + 0 * HF, h1, N, C, E, stats0, nullptr, nullptr, nullptr);
        bn_finalize_kernel<<<1, 64, 0, stream>>>(stats0, gamma + 0 * HF, beta + 0 * HF, ss0, invN, SREP);

        // layer 1: h1 -> h0, stats1
        conv_chunked_kernel<true, true, false><<<gN, BLK, 0, stream>>>(h1, rp2, csr2,
            ss0, convW1 + 1 * HF * HF, convb1 + 1 * HF, convW2 + 1 * HF * HF,
            convb2 + 1 * HF, h0, N, C, E, stats1, nullptr, nullptr, nullptr);
        bn_finalize_kernel<<<1, 64, 0, stream>>>(stats1, gamma + 1 * HF, beta + 1 * HF, ss1, invN, SREP);

        // layer 2: h0 -> pooled
        conv_chunked_kernel<true, false, true><<<gN, BLK, 0, stream>>>(h0, rp2, csr2,
            ss1, convW1 + 2 * HF * HF, convb1 + 2 * HF, convW2 + 2 * HF * HF,
            convb2 + 2 * HF, nullptr, N, C, E, nullptr, batch, pool, cnt);

        head_kernel<<<gG, BLK, 0, stream>>>(pool, cnt, postW1, postb1, postW2, postb2,
                                            (float*)d_out, G);
    } else if (off2 <= ws_size) {
        // =================== tier 2 ===================
        int*    csr    = (int*)(base + csr_o2);
        __half* h0     = (__half*)(base + h0_o2);
        __half* h1     = (__half*)(base + h1_o2);
        int*    deg    = (int*)(base + deg_o2);
        int*    rowptr = (int*)(base + row_o2);
        int*    cursor = (int*)(base + cur_o2);
        int*    bsum   = (int*)(base + bs_o2);
        float*  small  = (float*)(base + sm_o2);
        float* stats0 = small;
        float* stats1 = small + statsFloats;
        float* ss0    = small + 2 * statsFloats;
        float* ss1    = ss0 + 32;
        float* pool   = ss1 + 32 + 256;
        float* cnt    = pool + (size_t)G * HF;

        pre_mp_f16_kernel<<<gN, BLK, 0, stream>>>(x, preW, preb, h0, N);

        hipMemsetAsync(deg, 0, (size_t)N * 4, stream);
        hipMemsetAsync(stats0, 0, 2 * statsFloats * 4, stream);
        hipMemsetAsync(pool, 0, (size_t)G * (HF + 1) * 4, stream);
        hist_kernel<<<gE, BLK, 0, stream>>>(dst, deg, E);
        blocksum_kernel<<<gN, BLK, 0, stream>>>(deg, bsum, N);
        scan_bsum_kernel<<<1, 1024, 0, stream>>>(bsum, gN);
        rowptr_kernel<<<gN, BLK, 0, stream>>>(deg, bsum, rowptr, cursor, N);
        fill_kernel<<<gE, BLK, 0, stream>>>(src, dst, cursor, csr, E);

        conv_kernel<false, true, false><<<gN, BLK, 0, stream>>>(h0, rowptr, deg, csr, nullptr,
            convW1 + 0 * HF * HF, convb1 + 0 * HF, convW2 + 0 * HF * HF, convb2 + 0 * HF,
            h1, N, stats0, nullptr, nullptr, nullptr);
        bn_finalize_kernel<<<1, 64, 0, stream>>>(stats0, gamma + 0 * HF, beta + 0 * HF, ss0, invN, SREP);

        conv_kernel<true, true, false><<<gN, BLK, 0, stream>>>(h1, rowptr, deg, csr, ss0,
            convW1 + 1 * HF * HF, convb1 + 1 * HF, convW2 + 1 * HF * HF, convb2 + 1 * HF,
            h0, N, stats1, nullptr, nullptr, nullptr);
        bn_finalize_kernel<<<1, 64, 0, stream>>>(stats1, gamma + 1 * HF, beta + 1 * HF, ss1, invN, SREP);

        conv_kernel<true, false, true><<<gN, BLK, 0, stream>>>(h0, rowptr, deg, csr, ss1,
            convW1 + 2 * HF * HF, convb1 + 2 * HF, convW2 + 2 * HF * HF, convb2 + 2 * HF,
            nullptr, N, nullptr, batch, pool, cnt);

        head_kernel<<<gG, BLK, 0, stream>>>(pool, cnt, postW1, postb1, postW2, postb2,
                                            (float*)d_out, G);
    } else {
        // =================== tier 3 ===================
        size_t nh = (size_t)N * HF * sizeof(float);
        float* buf0 = (float*)base;
        float* buf1 = (float*)(base + nh);
        float* small = (float*)(base + 2 * nh);
        float* stats = small;          // 32 floats, [j],[16+j]
        float* ss0   = small + 32;
        float* ss1   = small + 64;
        float* pool  = small + 96;
        float* cnt   = pool + (size_t)G * HF;

        pre_mp_kernel<<<gN, BLK, 0, stream>>>(x, preW, preb, buf0, N);

        hipMemsetAsync(buf1, 0, nh, stream);
        hipMemsetAsync(stats, 0, 32 * 4, stream);
        scatter_kernel<false><<<gE, BLK, 0, stream>>>(src, dst, buf0, nullptr, buf1, E);
        update_kernel<false, true><<<gN, BLK, 0, stream>>>(buf0, buf1, nullptr,
            convW1 + 0 * HF * HF, convb1 + 0 * HF, convW2 + 0 * HF * HF, convb2 + 0 * HF,
            buf1, N, stats);
        bn_finalize_kernel<<<1, 64, 0, stream>>>(stats, gamma + 0 * HF, beta + 0 * HF, ss0, invN, 1);

        hipMemsetAsync(buf0, 0, nh, stream);
        hipMemsetAsync(stats, 0, 32 * 4, stream);
        scatter_kernel<true><<<gE, BLK, 0, stream>>>(src, dst, buf1, ss0, buf0, E);
        update_kernel<true, true><<<gN, BLK, 0, stream>>>(buf1, buf0, ss0,
            convW1 + 1 * HF * HF, convb1 + 1 * HF, convW2 + 1 * HF * HF, convb2 + 1 * HF,
            buf0, N, stats);
        bn_finalize_kernel<<<1, 64, 0, stream>>>(stats, gamma + 1 * HF, beta + 1 * HF, ss1, invN, 1);

        hipMemsetAsync(buf1, 0, nh, stream);
        scatter_kernel<true><<<gE, BLK, 0, stream>>>(src, dst, buf0, ss1, buf1, E);
        update_kernel<true, false><<<gN, BLK, 0, stream>>>(buf0, buf1, ss1,
            convW1 + 2 * HF * HF, convb1 + 2 * HF, convW2 + 2 * HF * HF, convb2 + 2 * HF,
            buf1, N, nullptr);

        hipMemsetAsync(pool, 0, (size_t)G * (HF + 1) * sizeof(float), stream);
        pool_atomic_kernel<<<gN, BLK, 0, stream>>>(buf1, batch, pool, cnt, N);
        head_kernel<<<gG, BLK, 0, stream>>>(pool, cnt, postW1, postb1, postW2, postb2,
                                            (float*)d_out, G);
    }
}

// Round 13
// 685.097 us; speedup vs baseline: 1.1877x; 1.1877x over previous
//
#include <hip/hip_runtime.h>
#include <hip/hip_fp16.h>

// GIN regression: pre-MLP -> 3x GINConv (BN folded) -> mean-pool -> head.
// Tier 1 (round-13 = round-11 + UB16 conv): 3-level atomic-free CSR build (EPB=4096)
//   producing per-dst lists sorted by coarse src chunk; conv = single flat kernel,
//   UB=16 batched gather (16 row loads in flight/lane), replicated BN-stats, segmented pool.
// Tier 2: plain gather conv. Tier 3: round-1 scatter/update.

static constexpr int HF = 10;    // hidden features
static constexpr int HPH = 16;   // padded fp16 row stride in halfs (32 B)
static constexpr int FIN = 16;   // input features
static constexpr int BLK = 256;
static constexpr int UB = 8;     // tier-2 gather batch
static constexpr int UBS = 16;   // tier-1 conv gather batch (round-13: was 8)
static constexpr int SREP = 128; // stats replicas (x32 floats each)
static constexpr int BWB = 13;   // bucket window bits (8192 dsts/bucket)
static constexpr int SRB = 19;   // src bits in packed word (N must be <= 2^19)
static constexpr int EPB = 4096; // edges per partition block

static inline size_t alignup(size_t x) { return (x + 255) & ~(size_t)255; }

__device__ inline void unpack_add(uint4 a, uint a2, float* z) {
    float2 t;
    t = __half22float2(*reinterpret_cast<const __half2*>(&a.x)); z[0] += t.x; z[1] += t.y;
    t = __half22float2(*reinterpret_cast<const __half2*>(&a.y)); z[2] += t.x; z[3] += t.y;
    t = __half22float2(*reinterpret_cast<const __half2*>(&a.z)); z[4] += t.x; z[5] += t.y;
    t = __half22float2(*reinterpret_cast<const __half2*>(&a.w)); z[6] += t.x; z[7] += t.y;
    t = __half22float2(*reinterpret_cast<const __half2*>(&a2));  z[8] += t.x; z[9] += t.y;
}

__device__ inline void unpack_fma(uint4 a, uint a2, float w, float* z) {
    float2 t;
    t = __half22float2(*reinterpret_cast<const __half2*>(&a.x)); z[0] = fmaf(w, t.x, z[0]); z[1] = fmaf(w, t.y, z[1]);
    t = __half22float2(*reinterpret_cast<const __half2*>(&a.y)); z[2] = fmaf(w, t.x, z[2]); z[3] = fmaf(w, t.y, z[3]);
    t = __half22float2(*reinterpret_cast<const __half2*>(&a.z)); z[4] = fmaf(w, t.x, z[4]); z[5] = fmaf(w, t.y, z[5]);
    t = __half22float2(*reinterpret_cast<const __half2*>(&a.w)); z[6] = fmaf(w, t.x, z[6]); z[7] = fmaf(w, t.y, z[7]);
    t = __half22float2(*reinterpret_cast<const __half2*>(&a2));  z[8] = fmaf(w, t.x, z[8]); z[9] = fmaf(w, t.y, z[9]);
}

__device__ inline void store_row_f16(__half* row, const float* o) {
    __half2 p01 = __floats2half2_rn(o[0], o[1]);
    __half2 p23 = __floats2half2_rn(o[2], o[3]);
    __half2 p45 = __floats2half2_rn(o[4], o[5]);
    __half2 p67 = __floats2half2_rn(o[6], o[7]);
    __half2 p89 = __floats2half2_rn(o[8], o[9]);
    uint4 w;
    w.x = *reinterpret_cast<uint*>(&p01);
    w.y = *reinterpret_cast<uint*>(&p23);
    w.z = *reinterpret_cast<uint*>(&p45);
    w.w = *reinterpret_cast<uint*>(&p67);
    *reinterpret_cast<uint4*>(row) = w;
    *reinterpret_cast<uint*>(row + 8) = *reinterpret_cast<uint*>(&p89);
}

// Stats: wave shuffle -> LDS block reduce -> 1 atomic set/block into replica slot.
__device__ inline void stats_block_reduce(const float* o, float* stats) {
    __shared__ float sred[BLK / 64][32];
#pragma unroll
    for (int j = 0; j < HF; ++j) {
        float s = o[j];
        float q = o[j] * o[j];
#pragma unroll
        for (int off = 32; off > 0; off >>= 1) {
            s += __shfl_down(s, off);
            q += __shfl_down(q, off);
        }
        if ((threadIdx.x & 63) == 0) {
            sred[threadIdx.x >> 6][j] = s;
            sred[threadIdx.x >> 6][16 + j] = q;
        }
    }
    __syncthreads();
    int t = threadIdx.x;
    if (t < 32) {
        bool lo = (t < HF);
        bool hi = (t >= 16 && t < 16 + HF);
        if (lo || hi) {
            float v = sred[0][t] + sred[1][t] + sred[2][t] + sred[3][t];
            unsafeAtomicAdd(&stats[(blockIdx.x & (SREP - 1)) * 32 + t], v);
        }
    }
}

// ---------------- pre_mp ----------------
__global__ void pre_mp_f16_kernel(const float* __restrict__ x, const float* __restrict__ W,
                                  const float* __restrict__ b, __half* __restrict__ h, int N) {
    int i = blockIdx.x * blockDim.x + threadIdx.x;
    if (i >= N) return;
    const float4* xr = (const float4*)(x + (size_t)i * FIN);
    float xv[FIN];
    float4 x0 = xr[0], x1 = xr[1], x2 = xr[2], x3 = xr[3];
    xv[0]=x0.x; xv[1]=x0.y; xv[2]=x0.z; xv[3]=x0.w;
    xv[4]=x1.x; xv[5]=x1.y; xv[6]=x1.z; xv[7]=x1.w;
    xv[8]=x2.x; xv[9]=x2.y; xv[10]=x2.z; xv[11]=x2.w;
    xv[12]=x3.x; xv[13]=x3.y; xv[14]=x3.z; xv[15]=x3.w;
    float acc[HF];
#pragma unroll
    for (int j = 0; j < HF; ++j) acc[j] = b[j];
#pragma unroll
    for (int k = 0; k < FIN; ++k) {
#pragma unroll
        for (int j = 0; j < HF; ++j) acc[j] = fmaf(xv[k], W[k * HF + j], acc[j]);
    }
    store_row_f16(h + (size_t)i * HPH, acc);
}

__global__ void pre_mp_kernel(const float* __restrict__ x, const float* __restrict__ W,
                              const float* __restrict__ b, float* __restrict__ h, int N) {
    int i = blockIdx.x * blockDim.x + threadIdx.x;
    if (i >= N) return;
    const float4* xr = (const float4*)(x + (size_t)i * FIN);
    float xv[FIN];
    float4 x0 = xr[0], x1 = xr[1], x2 = xr[2], x3 = xr[3];
    xv[0]=x0.x; xv[1]=x0.y; xv[2]=x0.z; xv[3]=x0.w;
    xv[4]=x1.x; xv[5]=x1.y; xv[6]=x1.z; xv[7]=x1.w;
    xv[8]=x2.x; xv[9]=x2.y; xv[10]=x2.z; xv[11]=x2.w;
    xv[12]=x3.x; xv[13]=x3.y; xv[14]=x3.z; xv[15]=x3.w;
    float acc[HF];
#pragma unroll
    for (int j = 0; j < HF; ++j) acc[j] = b[j];
#pragma unroll
    for (int k = 0; k < FIN; ++k) {
#pragma unroll
        for (int j = 0; j < HF; ++j) acc[j] = fmaf(xv[k], W[k * HF + j], acc[j]);
    }
    float* hr = h + (size_t)i * HF;
#pragma unroll
    for (int j = 0; j < HF; ++j) hr[j] = acc[j];
}

// ---------------- scan machinery (tier-2) ----------------
__global__ void blocksum_kernel(const int* __restrict__ deg, int* __restrict__ bsum, int M) {
    int i = blockIdx.x * BLK + threadIdx.x;
    int v = (i < M) ? deg[i] : 0;
#pragma unroll
    for (int off = 32; off > 0; off >>= 1) v += __shfl_down(v, off);
    __shared__ int sm[BLK / 64];
    if ((threadIdx.x & 63) == 0) sm[threadIdx.x >> 6] = v;
    __syncthreads();
    if (threadIdx.x == 0) {
        int t = 0;
#pragma unroll
        for (int w = 0; w < BLK / 64; ++w) t += sm[w];
        bsum[blockIdx.x] = t;
    }
}

__global__ void scan_bsum_kernel(int* __restrict__ bs, int nb) {
    __shared__ int sm[1024];
    int running = 0;
    for (int base = 0; base < nb; base += 1024) {
        int i = base + (int)threadIdx.x;
        int v = (i < nb) ? bs[i] : 0;
        sm[threadIdx.x] = v;
        __syncthreads();
        for (int off = 1; off < 1024; off <<= 1) {
            int t = (threadIdx.x >= (unsigned)off) ? sm[threadIdx.x - off] : 0;
            __syncthreads();
            sm[threadIdx.x] += t;
            __syncthreads();
        }
        int incl = sm[threadIdx.x];
        if (i < nb) bs[i] = running + incl - v;  // exclusive
        int chunk_total = sm[1023];
        __syncthreads();
        running += chunk_total;
    }
}

__global__ void rowptr_kernel(const int* __restrict__ deg, const int* __restrict__ bsum,
                              int* __restrict__ rowptr, int* cursor, int M) {
    int i = blockIdx.x * BLK + threadIdx.x;
    int v = (i < M) ? deg[i] : 0;
    __shared__ int sm[BLK];
    sm[threadIdx.x] = v;
    __syncthreads();
    for (int off = 1; off < BLK; off <<= 1) {
        int t = (threadIdx.x >= (unsigned)off) ? sm[threadIdx.x - off] : 0;
        __syncthreads();
        sm[threadIdx.x] += t;
        __syncthreads();
    }
    int excl = sm[threadIdx.x] - v + bsum[blockIdx.x];
    if (i < M) {
        rowptr[i] = excl;
        cursor[i] = excl;
    }
}

// ---------------- atomic-free 3-level CSR build (tier-1) ----------------
__global__ void bucket_hist_kernel(const int* __restrict__ dst, int* __restrict__ bcount,
                                   int E, int B) {
    __shared__ int lcount[64];
    if (threadIdx.x < B) lcount[threadIdx.x] = 0;
    __syncthreads();
    int start = blockIdx.x * EPB;
    int end = min(start + EPB, E);
    for (int e = start + threadIdx.x; e < end; e += BLK)
        atomicAdd(&lcount[dst[e] >> BWB], 1);
    __syncthreads();
    if (threadIdx.x < B && lcount[threadIdx.x] > 0)
        atomicAdd(&bcount[threadIdx.x], lcount[threadIdx.x]);
}

__global__ void bucket_scan_kernel(const int* __restrict__ bcount, int* __restrict__ bbase,
                                   int* __restrict__ bcursor, int B) {
    if (threadIdx.x == 0) {
        int run = 0;
        for (int b = 0; b < B; ++b) {
            bbase[b] = run;
            bcursor[b] = run;
            run += bcount[b];
        }
        bbase[B] = run;
    }
}

// L1: partition into buckets; packed = (dst_low << SRB) | src
__global__ void partition_kernel(const int* __restrict__ src, const int* __restrict__ dst,
                                 int* __restrict__ bcursor, uint* __restrict__ packed,
                                 int E, int B) {
    __shared__ int lcount[64], lbase[64], lcur[64];
    int start = blockIdx.x * EPB;
    int end = min(start + EPB, E);
    if (threadIdx.x < B) lcount[threadIdx.x] = 0;
    __syncthreads();
    for (int e = start + threadIdx.x; e < end; e += BLK)
        atomicAdd(&lcount[dst[e] >> BWB], 1);
    __syncthreads();
    if (threadIdx.x < B) {
        lbase[threadIdx.x] = (lcount[threadIdx.x] > 0)
                           ? atomicAdd(&bcursor[threadIdx.x], lcount[threadIdx.x]) : 0;
        lcur[threadIdx.x] = 0;
    }
    __syncthreads();
    for (int e = start + threadIdx.x; e < end; e += BLK) {
        int d = dst[e];
        int b = d >> BWB;
        int p = lbase[b] + atomicAdd(&lcur[b], 1);
        packed[p] = ((uint)(d & ((1 << BWB) - 1)) << SRB) | (uint)src[e];
    }
}

__device__ inline int find_bucket(const int* sbase, int B, int p) {
    int lo = 0, hi = B;
    while (hi - lo > 1) {
        int mid = (lo + hi) >> 1;
        if (p >= sbase[mid]) lo = mid; else hi = mid;
    }
    return lo;
}

// L2 hist: group = (bucket<<6) | (dst_low>>7)
__global__ void l2_hist_kernel(const uint* __restrict__ packed1, const int* __restrict__ bbase,
                               int* __restrict__ gcount, int E, int B) {
    __shared__ int sbase[65];
    __shared__ int lcount[128];
    __shared__ int g0s;
    if (threadIdx.x <= B) sbase[threadIdx.x] = bbase[threadIdx.x];
    if (threadIdx.x < 128) lcount[threadIdx.x] = 0;
    __syncthreads();
    int start = blockIdx.x * EPB;
    int end = min(start + EPB, E);
    if (start >= E) return;
    if (threadIdx.x == 0) g0s = find_bucket(sbase, B, start) << 6;
    __syncthreads();
    int g0 = g0s;
    for (int p = start + threadIdx.x; p < end; p += BLK) {
        uint v = packed1[p];
        int b = find_bucket(sbase, B, p);
        int g = (b << 6) | (((int)(v >> SRB)) >> 7);
        atomicAdd(&lcount[g - g0], 1);
    }
    __syncthreads();
    if (threadIdx.x < 128 && lcount[threadIdx.x] > 0)
        atomicAdd(&gcount[g0 + threadIdx.x], lcount[threadIdx.x]);
}

__global__ void l2_scan_kernel(const int* __restrict__ gcount, int* __restrict__ gbase,
                               int* __restrict__ gcursor, int NG) {
    __shared__ int sm[1024];
    int running = 0;
    for (int b0 = 0; b0 < NG; b0 += 1024) {
        int i = b0 + (int)threadIdx.x;
        int v = (i < NG) ? gcount[i] : 0;
        sm[threadIdx.x] = v;
        __syncthreads();
        for (int off = 1; off < 1024; off <<= 1) {
            int t = (threadIdx.x >= (unsigned)off) ? sm[threadIdx.x - off] : 0;
            __syncthreads();
            sm[threadIdx.x] += t;
            __syncthreads();
        }
        int incl = sm[threadIdx.x];
        if (i < NG) { gbase[i] = running + incl - v; gcursor[i] = running + incl - v; }
        int tot = sm[1023];
        __syncthreads();
        running += tot;
    }
    if (threadIdx.x == 0) gbase[NG] = running;
}

// L2 place: per-block partition into groups (single-XCD output regions)
__global__ void l2_place_kernel(const uint* __restrict__ packed1, const int* __restrict__ bbase,
                                int* __restrict__ gcursor, uint* __restrict__ packed2,
                                int E, int B) {
    __shared__ int sbase[65];
    __shared__ int lcount[128], lbase[128], lcur[128];
    __shared__ int g0s;
    if (threadIdx.x <= B) sbase[threadIdx.x] = bbase[threadIdx.x];
    if (threadIdx.x < 128) lcount[threadIdx.x] = 0;
    __syncthreads();
    int start = blockIdx.x * EPB;
    int end = min(start + EPB, E);
    if (start >= E) return;
    if (threadIdx.x == 0) g0s = find_bucket(sbase, B, start) << 6;
    __syncthreads();
    int g0 = g0s;
    for (int p = start + threadIdx.x; p < end; p += BLK) {
        uint v = packed1[p];
        int b = find_bucket(sbase, B, p);
        int bin = ((b << 6) | (((int)(v >> SRB)) >> 7)) - g0;
        atomicAdd(&lcount[bin], 1);
    }
    __syncthreads();
    if (threadIdx.x < 128) {
        lbase[threadIdx.x] = (lcount[threadIdx.x] > 0)
                           ? atomicAdd(&gcursor[g0 + threadIdx.x], lcount[threadIdx.x]) : 0;
        lcur[threadIdx.x] = 0;
    }
    __syncthreads();
    for (int p = start + threadIdx.x; p < end; p += BLK) {
        uint v = packed1[p];
        int b = find_bucket(sbase, B, p);
        int bin = ((b << 6) | (((int)(v >> SRB)) >> 7)) - g0;
        packed2[lbase[bin] + atomicAdd(&lcur[bin], 1)] = v;
    }
}

// L3: one block per group (~2K edges, 128 dsts). LDS sort by (dst&127)*C + chunk;
// plain stores of csr2; writes per-dst rowptr (start of each dst's sorted list).
__global__ void l3_sort_kernel(const uint* __restrict__ packed2, const int* __restrict__ gbase,
                               int* __restrict__ csr2, int* __restrict__ rowptr,
                               int N, int C, int cbits, int E) {
    __shared__ int cnt[1024];
    __shared__ int bas[1024];
    __shared__ int tsum[256];
    int g = blockIdx.x;
    int start = gbase[g], end = gbase[g + 1];
    int dstbase = g << 7;
    for (int t = threadIdx.x; t < 1024; t += BLK) cnt[t] = 0;
    __syncthreads();
    for (int p = start + (int)threadIdx.x; p < end; p += BLK) {
        uint v = packed2[p];
        int s = (int)(v & ((1u << SRB) - 1));
        int dl7 = ((int)(v >> SRB)) & 127;
        atomicAdd(&cnt[dl7 * C + (s >> cbits)], 1);
    }
    __syncthreads();
    int tid = threadIdx.x;
    int c0 = cnt[4 * tid], c1 = cnt[4 * tid + 1], c2 = cnt[4 * tid + 2], c3 = cnt[4 * tid + 3];
    int mysum = c0 + c1 + c2 + c3;
    tsum[tid] = mysum;
    __syncthreads();
    for (int off = 1; off < 256; off <<= 1) {
        int t2 = (tid >= off) ? tsum[tid - off] : 0;
        __syncthreads();
        tsum[tid] += t2;
        __syncthreads();
    }
    int excl = tsum[tid] - mysum;
    bas[4 * tid] = excl;
    bas[4 * tid + 1] = excl + c0;
    bas[4 * tid + 2] = excl + c0 + c1;
    bas[4 * tid + 3] = excl + c0 + c1 + c2;
    __syncthreads();
    // per-dst rowptr (start of this dst's full sorted list)
    for (int t = threadIdx.x; t < 128; t += BLK) {
        int dstn = dstbase + t;
        if (dstn < N) rowptr[dstn] = start + bas[t * C];
    }
    // reuse cnt as cursor
    for (int t = threadIdx.x; t < 1024; t += BLK) cnt[t] = 0;
    __syncthreads();
    for (int p = start + (int)threadIdx.x; p < end; p += BLK) {
        uint v = packed2[p];
        int s = (int)(v & ((1u << SRB) - 1));
        int dl7 = ((int)(v >> SRB)) & 127;
        int key = dl7 * C + (s >> cbits);
        int pos = start + bas[key] + atomicAdd(&cnt[key], 1);
        csr2[pos] = s;
    }
}

// tier-2 CSR build
__global__ void hist_kernel(const int* __restrict__ idx, int* __restrict__ deg, int E) {
    int e = blockIdx.x * blockDim.x + threadIdx.x;
    if (e >= E) return;
    atomicAdd(&deg[idx[e]], 1);
}

__global__ void fill_kernel(const int* __restrict__ src, const int* __restrict__ dst,
                            int* __restrict__ cursor, int* __restrict__ csr, int E) {
    int e = blockIdx.x * blockDim.x + threadIdx.x;
    if (e >= E) return;
    int pos = atomicAdd(&cursor[dst[e]], 1);
    csr[pos] = src[e];
}

// ---------------- tier-1 fused conv over the sorted CSR (UB=16) ----------------
template <bool BN, bool STATS, bool POOL>
__global__ void __launch_bounds__(BLK) conv_sorted_kernel(
        const __half* __restrict__ hin, const int* __restrict__ rowptr,
        const int* __restrict__ csr, const float* __restrict__ ss,
        const float* __restrict__ W1, const float* __restrict__ b1,
        const float* __restrict__ W2, const float* __restrict__ b2,
        __half* __restrict__ hout, int N, int E, float* stats,
        const int* __restrict__ batch, float* pool, float* cnt) {
    int i = blockIdx.x * blockDim.x + threadIdx.x;
    bool act = i < N;
    float o[HF];
    int g = 0x7fffffff;
    if (act) {
        float z[HF];
#pragma unroll
        for (int j = 0; j < HF; ++j) z[j] = 0.0f;
        {
            const __half* hp = hin + (size_t)i * HPH;
            uint4 r = *reinterpret_cast<const uint4*>(hp);
            uint r2 = *reinterpret_cast<const uint*>(hp + 8);
            unpack_add(r, r2, z);
        }
        int base = rowptr[i];
        int end = (i + 1 < N) ? rowptr[i + 1] : E;
        int d = end - base;
        for (int k0 = 0; k0 < d; k0 += UBS) {
            int s[UBS];
            float w[UBS];
#pragma unroll
            for (int u = 0; u < UBS; ++u) {
                int kk = k0 + u;
                int kc = kk < d ? kk : d - 1;
                s[u] = csr[base + kc];
                w[u] = kk < d ? 1.0f : 0.0f;
            }
            uint4 a[UBS];
            uint a2[UBS];
#pragma unroll
            for (int u = 0; u < UBS; ++u) {
                const __half* sp = hin + (size_t)s[u] * HPH;
                a[u]  = *reinterpret_cast<const uint4*>(sp);
                a2[u] = *reinterpret_cast<const uint*>(sp + 8);
            }
#pragma unroll
            for (int u = 0; u < UBS; ++u) unpack_fma(a[u], a2[u], w[u], z);
        }
        if (BN) {
            float dp1 = (float)(d + 1);
#pragma unroll
            for (int j = 0; j < HF; ++j) z[j] = fmaf(z[j], ss[j], dp1 * ss[HF + j]);
        }
        float t[HF];
#pragma unroll
        for (int j = 0; j < HF; ++j) {
            float a = b1[j];
#pragma unroll
            for (int k = 0; k < HF; ++k) a = fmaf(z[k], W1[k * HF + j], a);
            t[j] = fmaxf(a, 0.0f);
        }
#pragma unroll
        for (int j = 0; j < HF; ++j) {
            float a = b2[j];
#pragma unroll
            for (int k = 0; k < HF; ++k) a = fmaf(t[k], W2[k * HF + j], a);
            o[j] = a;
        }
        if (!POOL) {
            store_row_f16(hout + (size_t)i * HPH, o);
        } else {
            g = batch[i];
        }
    } else {
#pragma unroll
        for (int j = 0; j < HF; ++j) o[j] = 0.0f;
    }
    if (STATS) stats_block_reduce(o, stats);
    if (POOL) {
        int lane = threadIdx.x & 63;
        float c1 = act ? 1.0f : 0.0f;
#pragma unroll
        for (int off = 1; off < 64; off <<= 1) {
            int gu = __shfl_up(g, off);
            float cu = __shfl_up(c1, off);
            bool take = (lane >= off) && (gu == g);
            if (take) c1 += cu;
#pragma unroll
            for (int j = 0; j < HF; ++j) {
                float vu = __shfl_up(o[j], off);
                if (take) o[j] += vu;
            }
        }
        int gn = __shfl_down(g, 1);
        bool last = (lane == 63) || (gn != g);
        if (act && last) {
#pragma unroll
            for (int j = 0; j < HF; ++j) unsafeAtomicAdd(&pool[(size_t)g * HF + j], o[j]);
            unsafeAtomicAdd(&cnt[g], c1);
        }
    }
}

// ---------------- tier-2 conv ----------------
template <bool BN, bool STATS, bool POOL>
__global__ void __launch_bounds__(BLK) conv_kernel(
                            const __half* __restrict__ hin,
                            const int* __restrict__ rowptr, const int* __restrict__ deg,
                            const int* __restrict__ csr, const float* __restrict__ ss,
                            const float* __restrict__ W1, const float* __restrict__ b1,
                            const float* __restrict__ W2, const float* __restrict__ b2,
                            __half* __restrict__ hout, int N, float* stats,
                            const int* __restrict__ batch, float* pool, float* cnt) {
    int i = blockIdx.x * blockDim.x + threadIdx.x;
    bool act = i < N;
    float o[HF];
    int g = 0x7fffffff;
    if (act) {
        float z[HF];
#pragma unroll
        for (int j = 0; j < HF; ++j) z[j] = 0.0f;
        {
            const __half* hp = hin + (size_t)i * HPH;
            uint4 r = *reinterpret_cast<const uint4*>(hp);
            uint r2 = *reinterpret_cast<const uint*>(hp + 8);
            unpack_add(r, r2, z);
        }
        int base = rowptr[i];
        int d = deg[i];
        for (int k0 = 0; k0 < d; k0 += UB) {
            int s[UB];
            float w[UB];
#pragma unroll
            for (int u = 0; u < UB; ++u) {
                int kk = k0 + u;
                int kc = kk < d ? kk : d - 1;
                s[u] = csr[base + kc];
                w[u] = kk < d ? 1.0f : 0.0f;
            }
            uint4 a[UB];
            uint a2[UB];
#pragma unroll
            for (int u = 0; u < UB; ++u) {
                const __half* sp = hin + (size_t)s[u] * HPH;
                a[u]  = *reinterpret_cast<const uint4*>(sp);
                a2[u] = *reinterpret_cast<const uint*>(sp + 8);
            }
#pragma unroll
            for (int u = 0; u < UB; ++u) unpack_fma(a[u], a2[u], w[u], z);
        }
        if (BN) {
            float dp1 = (float)(d + 1);
#pragma unroll
            for (int j = 0; j < HF; ++j) z[j] = fmaf(z[j], ss[j], dp1 * ss[HF + j]);
        }
        float t[HF];
#pragma unroll
        for (int j = 0; j < HF; ++j) {
            float a = b1[j];
#pragma unroll
            for (int k = 0; k < HF; ++k) a = fmaf(z[k], W1[k * HF + j], a);
            t[j] = fmaxf(a, 0.0f);
        }
#pragma unroll
        for (int j = 0; j < HF; ++j) {
            float a = b2[j];
#pragma unroll
            for (int k = 0; k < HF; ++k) a = fmaf(t[k], W2[k * HF + j], a);
            o[j] = a;
        }
        if (!POOL) {
            store_row_f16(hout + (size_t)i * HPH, o);
        } else {
            g = batch[i];
        }
    } else {
#pragma unroll
        for (int j = 0; j < HF; ++j) o[j] = 0.0f;
    }
    if (STATS) stats_block_reduce(o, stats);
    if (POOL) {
        int lane = threadIdx.x & 63;
        float c1 = act ? 1.0f : 0.0f;
#pragma unroll
        for (int off = 1; off < 64; off <<= 1) {
            int gu = __shfl_up(g, off);
            float cu = __shfl_up(c1, off);
            bool take = (lane >= off) && (gu == g);
            if (take) c1 += cu;
#pragma unroll
            for (int j = 0; j < HF; ++j) {
                float vu = __shfl_up(o[j], off);
                if (take) o[j] += vu;
            }
        }
        int gn = __shfl_down(g, 1);
        bool last = (lane == 63) || (gn != g);
        if (act && last) {
#pragma unroll
            for (int j = 0; j < HF; ++j) unsafeAtomicAdd(&pool[(size_t)g * HF + j], o[j]);
            unsafeAtomicAdd(&cnt[g], c1);
        }
    }
}

// ---------------- BN finalize (sums R replica slots) / head ----------------
__global__ void bn_finalize_kernel(const float* __restrict__ stats,
                                   const float* __restrict__ gamma,
                                   const float* __restrict__ beta,
                                   float* __restrict__ ss, float invN, int R) {
    int j = threadIdx.x;
    if (j >= HF) return;
    float sm = 0.0f, sq = 0.0f;
    for (int r = 0; r < R; ++r) {
        sm += stats[r * 32 + j];
        sq += stats[r * 32 + 16 + j];
    }
    float mean = sm * invN;
    float var = sq * invN - mean * mean;
    float sc = gamma[j] * rsqrtf(var + 1e-5f);
    ss[j] = sc;
    ss[HF + j] = beta[j] - mean * sc;
}

__global__ void head_kernel(const float* __restrict__ pool, const float* __restrict__ cnt,
                            const float* __restrict__ W1, const float* __restrict__ b1,
                            const float* __restrict__ W2, const float* __restrict__ b2,
                            float* __restrict__ out, int G) {
    int g = blockIdx.x * blockDim.x + threadIdx.x;
    if (g >= G) return;
    float inv = 1.0f / fmaxf(cnt[g], 1.0f);
    float p[HF];
    const float* pr = pool + (size_t)g * HF;
#pragma unroll
    for (int j = 0; j < HF; ++j) p[j] = pr[j] * inv;
    float acc = b2[0];
#pragma unroll
    for (int j = 0; j < HF; ++j) {
        float a = b1[j];
#pragma unroll
        for (int k = 0; k < HF; ++k) a = fmaf(p[k], W1[k * HF + j], a);
        acc = fmaf(fmaxf(a, 0.0f), W2[j], acc);
    }
    out[g] = acc;
}

// ================= tier-3 (round-1, stats layout [j],[16+j], R=1) ========
template <bool BN>
__global__ void scatter_kernel(const int* __restrict__ src, const int* __restrict__ dst,
                               const float* __restrict__ h, const float* __restrict__ ss,
                               float* agg, int E) {
    int e = blockIdx.x * blockDim.x + threadIdx.x;
    if (e >= E) return;
    int s = src[e];
    int d = dst[e];
    const float* hr = h + (size_t)s * HF;
    float* ar = agg + (size_t)d * HF;
#pragma unroll
    for (int j = 0; j < HF; ++j) {
        float v = hr[j];
        if (BN) v = fmaf(v, ss[j], ss[HF + j]);
        unsafeAtomicAdd(&ar[j], v);
    }
}

template <bool BN, bool STATS>
__global__ void update_kernel(const float* __restrict__ h, const float* agg,
                              const float* __restrict__ ss,
                              const float* __restrict__ W1, const float* __restrict__ b1,
                              const float* __restrict__ W2, const float* __restrict__ b2,
                              float* out, int N, float* stats) {
    int i = blockIdx.x * blockDim.x + threadIdx.x;
    float o[HF];
    bool act = (i < N);
    if (act) {
        float z[HF];
        const float* hr = h + (size_t)i * HF;
        const float* ar = agg + (size_t)i * HF;
#pragma unroll
        for (int j = 0; j < HF; ++j) {
            float v = hr[j];
            if (BN) v = fmaf(v, ss[j], ss[HF + j]);
            z[j] = v + ar[j];
        }
        float t[HF];
#pragma unroll
        for (int j = 0; j < HF; ++j) {
            float a = b1[j];
#pragma unroll
            for (int k = 0; k < HF; ++k) a = fmaf(z[k], W1[k * HF + j], a);
            t[j] = fmaxf(a, 0.0f);
        }
        float* orow = out + (size_t)i * HF;
#pragma unroll
        for (int j = 0; j < HF; ++j) {
            float a = b2[j];
#pragma unroll
            for (int k = 0; k < HF; ++k) a = fmaf(t[k], W2[k * HF + j], a);
            o[j] = a;
            orow[j] = a;
        }
    } else {
#pragma unroll
        for (int j = 0; j < HF; ++j) o[j] = 0.0f;
    }
    if (STATS) {
#pragma unroll
        for (int j = 0; j < HF; ++j) {
            float s = o[j];
            float q = o[j] * o[j];
#pragma unroll
            for (int off = 32; off > 0; off >>= 1) {
                s += __shfl_down(s, off);
                q += __shfl_down(q, off);
            }
            if ((threadIdx.x & 63) == 0) {
                unsafeAtomicAdd(&stats[j], s);
                unsafeAtomicAdd(&stats[16 + j], q);
            }
        }
    }
}

__global__ void pool_atomic_kernel(const float* __restrict__ h, const int* __restrict__ batch,
                                   float* pool, float* cnt, int N) {
    int i = blockIdx.x * blockDim.x + threadIdx.x;
    if (i >= N) return;
    int g = batch[i];
    const float* hr = h + (size_t)i * HF;
    float* pr = pool + (size_t)g * HF;
#pragma unroll
    for (int j = 0; j < HF; ++j) unsafeAtomicAdd(&pr[j], hr[j]);
    unsafeAtomicAdd(&cnt[g], 1.0f);
}

extern "C" void kernel_launch(void* const* d_in, const int* in_sizes, int n_in,
                              void* d_out, int out_size, void* d_ws, size_t ws_size,
                              hipStream_t stream) {
    const float* x      = (const float*)d_in[0];
    const int*   ei     = (const int*)d_in[1];
    const int*   batch  = (const int*)d_in[2];
    const float* preW   = (const float*)d_in[3];
    const float* preb   = (const float*)d_in[4];
    const float* convW1 = (const float*)d_in[5];
    const float* convb1 = (const float*)d_in[6];
    const float* convW2 = (const float*)d_in[7];
    const float* convb2 = (const float*)d_in[8];
    const float* gamma  = (const float*)d_in[9];
    const float* beta   = (const float*)d_in[10];
    const float* postW1 = (const float*)d_in[11];
    const float* postb1 = (const float*)d_in[12];
    const float* postW2 = (const float*)d_in[13];
    const float* postb2 = (const float*)d_in[14];

    const int N = in_sizes[0] / FIN;
    const int E = in_sizes[1] / 2;
    const int G = out_size;
    const int* src = ei;
    const int* dst = ei + E;

    const int gN = (N + BLK - 1) / BLK;
    const int gE = (E + BLK - 1) / BLK;
    const int gG = (G + BLK - 1) / BLK;
    const int gP = (E + EPB - 1) / EPB;
    const float invN = 1.0f / (float)N;
    char* base = (char*)d_ws;

    const size_t statsFloats = (size_t)SREP * 32;
    const size_t smallFloats = 2 * statsFloats + 64 + 256 + (size_t)G * (HF + 1);

    // ---- tier-1 layout ----
    const int cbits = 16;
    const int C = (N + (1 << cbits) - 1) >> cbits;
    const int B = (N + (1 << BWB) - 1) >> BWB;
    const int NG = B * 64;
    size_t ebytes = alignup((size_t)E * 4);

    size_t off1 = 0;
    auto take1 = [&](size_t bytes) { size_t o = off1; off1 += alignup(bytes); return o; };
    size_t pk1_o  = take1(ebytes);                // packed1, then csr2 (aliased)
    size_t pk2_o  = take1(ebytes);                // packed2
    size_t h0_o1  = take1((size_t)N * HPH * 2);
    size_t h1_o1  = take1((size_t)N * HPH * 2);
    size_t rp_o   = take1((size_t)(N + 4) * 4);
    size_t gg_o   = take1((size_t)(3 * NG + 8) * 4);   // gcount | gbase(NG+1) | gcursor
    size_t sm_o1  = take1(smallFloats * 4);

    // ---- tier-2 layout ----
    size_t off2 = 0;
    auto take2 = [&](size_t bytes) { size_t o = off2; off2 += alignup(bytes); return o; };
    size_t csr_o2 = take2((size_t)E * 4);
    size_t h0_o2  = take2((size_t)N * HPH * 2);
    size_t h1_o2  = take2((size_t)N * HPH * 2);
    size_t deg_o2 = take2((size_t)N * 4);
    size_t row_o2 = take2((size_t)N * 4);
    size_t cur_o2 = take2((size_t)N * 4);
    size_t bs_o2  = take2((size_t)gN * 4);
    size_t sm_o2  = take2(smallFloats * 4);

    bool tier1_ok = (off1 <= ws_size) && (C >= 2) && (C <= 8) && (B <= 64) &&
                    (N <= (1 << SRB));

    if (tier1_ok) {
        // =================== tier 1 ===================
        int*    csr2   = (int*)(base + pk1_o);           // aliases packed1
        uint*   packed1= (uint*)(base + pk1_o);
        uint*   packed2= (uint*)(base + pk2_o);
        __half* h0     = (__half*)(base + h0_o1);
        __half* h1     = (__half*)(base + h1_o1);
        int*    rowptr = (int*)(base + rp_o);
        int*    gcount = (int*)(base + gg_o);
        int*    gbase  = gcount + NG;                    // NG+1
        int*    gcursor= gbase + NG + 4;
        float*  small  = (float*)(base + sm_o1);
        float* stats0 = small;
        float* stats1 = small + statsFloats;
        float* ss0    = small + 2 * statsFloats;
        float* ss1    = ss0 + 32;
        int*   bcount = (int*)(ss1 + 32);        // 64
        int*   bbase  = bcount + 64;             // 65
        int*   bcursor= bbase + 66;              // 64
        float* pool   = (float*)(bcursor + 64 + 2);
        float* cnt    = pool + (size_t)G * HF;

        pre_mp_f16_kernel<<<gN, BLK, 0, stream>>>(x, preW, preb, h0, N);

        hipMemsetAsync(stats0, 0, 2 * statsFloats * 4, stream);
        hipMemsetAsync(bcount, 0, 64 * 4, stream);
        hipMemsetAsync(gcount, 0, (size_t)NG * 4, stream);
        hipMemsetAsync(pool, 0, (size_t)G * (HF + 1) * 4, stream);

        // atomic-free 3-level CSR build (sorted-by-src-chunk per-dst lists)
        bucket_hist_kernel<<<gP, BLK, 0, stream>>>(dst, bcount, E, B);
        bucket_scan_kernel<<<1, 64, 0, stream>>>(bcount, bbase, bcursor, B);
        partition_kernel<<<gP, BLK, 0, stream>>>(src, dst, bcursor, packed1, E, B);
        l2_hist_kernel<<<gP, BLK, 0, stream>>>(packed1, bbase, gcount, E, B);
        l2_scan_kernel<<<1, 1024, 0, stream>>>(gcount, gbase, gcursor, NG);
        l2_place_kernel<<<gP, BLK, 0, stream>>>(packed1, bbase, gcursor, packed2, E, B);
        l3_sort_kernel<<<NG, BLK, 0, stream>>>(packed2, gbase, csr2, rowptr, N, C, cbits, E);
        // packed1 consumed; csr2 occupies its region. packed2 dead after l3.

        // layer 0: h0 -> h1, stats0
        conv_sorted_kernel<false, true, false><<<gN, BLK, 0, stream>>>(h0, rowptr, csr2,
            nullptr, convW1 + 0 * HF * HF, convb1 + 0 * HF, convW2 + 0 * HF * HF,
            convb2 + 0 * HF, h1, N, E, stats0, nullptr, nullptr, nullptr);
        bn_finalize_kernel<<<1, 64, 0, stream>>>(stats0, gamma + 0 * HF, beta + 0 * HF, ss0, invN, SREP);

        // layer 1: h1 -> h0, stats1
        conv_sorted_kernel<true, true, false><<<gN, BLK, 0, stream>>>(h1, rowptr, csr2,
            ss0, convW1 + 1 * HF * HF, convb1 + 1 * HF, convW2 + 1 * HF * HF,
            convb2 + 1 * HF, h0, N, E, stats1, nullptr, nullptr, nullptr);
        bn_finalize_kernel<<<1, 64, 0, stream>>>(stats1, gamma + 1 * HF, beta + 1 * HF, ss1, invN, SREP);

        // layer 2: h0 -> pooled
        conv_sorted_kernel<true, false, true><<<gN, BLK, 0, stream>>>(h0, rowptr, csr2,
            ss1, convW1 + 2 * HF * HF, convb1 + 2 * HF, convW2 + 2 * HF * HF,
            convb2 + 2 * HF, nullptr, N, E, nullptr, batch, pool, cnt);

        head_kernel<<<gG, BLK, 0, stream>>>(pool, cnt, postW1, postb1, postW2, postb2,
                                            (float*)d_out, G);
    } else if (off2 <= ws_size) {
        // =================== tier 2 ===================
        int*    csr    = (int*)(base + csr_o2);
        __half* h0     = (__half*)(base + h0_o2);
        __half* h1     = (__half*)(base + h1_o2);
        int*    deg    = (int*)(base + deg_o2);
        int*    rowptr = (int*)(base + row_o2);
        int*    cursor = (int*)(base + cur_o2);
        int*    bsum   = (int*)(base + bs_o2);
        float*  small  = (float*)(base + sm_o2);
        float* stats0 = small;
        float* stats1 = small + statsFloats;
        float* ss0    = small + 2 * statsFloats;
        float* ss1    = ss0 + 32;
        float* pool   = ss1 + 32 + 256;
        float* cnt    = pool + (size_t)G * HF;

        pre_mp_f16_kernel<<<gN, BLK, 0, stream>>>(x, preW, preb, h0, N);

        hipMemsetAsync(deg, 0, (size_t)N * 4, stream);
        hipMemsetAsync(stats0, 0, 2 * statsFloats * 4, stream);
        hipMemsetAsync(pool, 0, (size_t)G * (HF + 1) * 4, stream);
        hist_kernel<<<gE, BLK, 0, stream>>>(dst, deg, E);
        blocksum_kernel<<<gN, BLK, 0, stream>>>(deg, bsum, N);
        scan_bsum_kernel<<<1, 1024, 0, stream>>>(bsum, gN);
        rowptr_kernel<<<gN, BLK, 0, stream>>>(deg, bsum, rowptr, cursor, N);
        fill_kernel<<<gE, BLK, 0, stream>>>(src, dst, cursor, csr, E);

        conv_kernel<false, true, false><<<gN, BLK, 0, stream>>>(h0, rowptr, deg, csr, nullptr,
            convW1 + 0 * HF * HF, convb1 + 0 * HF, convW2 + 0 * HF * HF, convb2 + 0 * HF,
            h1, N, stats0, nullptr, nullptr, nullptr);
        bn_finalize_kernel<<<1, 64, 0, stream>>>(stats0, gamma + 0 * HF, beta + 0 * HF, ss0, invN, SREP);

        conv_kernel<true, true, false><<<gN, BLK, 0, stream>>>(h1, rowptr, deg, csr, ss0,
            convW1 + 1 * HF * HF, convb1 + 1 * HF, convW2 + 1 * HF * HF, convb2 + 1 * HF,
            h0, N, stats1, nullptr, nullptr, nullptr);
        bn_finalize_kernel<<<1, 64, 0, stream>>>(stats1, gamma + 1 * HF, beta + 1 * HF, ss1, invN, SREP);

        conv_kernel<true, false, true><<<gN, BLK, 0, stream>>>(h0, rowptr, deg, csr, ss1,
            convW1 + 2 * HF * HF, convb1 + 2 * HF, convW2 + 2 * HF * HF, convb2 + 2 * HF,
            nullptr, N, nullptr, batch, pool, cnt);

        head_kernel<<<gG, BLK, 0, stream>>>(pool, cnt, postW1, postb1, postW2, postb2,
                                            (float*)d_out, G);
    } else {
        // =================== tier 3 ===================
        size_t nh = (size_t)N * HF * sizeof(float);
        float* buf0 = (float*)base;
        float* buf1 = (float*)(base + nh);
        float* small = (float*)(base + 2 * nh);
        float* stats = small;          // 32 floats, [j],[16+j]
        float* ss0   = small + 32;
        float* ss1   = small + 64;
        float* pool  = small + 96;
        float* cnt   = pool + (size_t)G * HF;

        pre_mp_kernel<<<gN, BLK, 0, stream>>>(x, preW, preb, buf0, N);

        hipMemsetAsync(buf1, 0, nh, stream);
        hipMemsetAsync(stats, 0, 32 * 4, stream);
        scatter_kernel<false><<<gE, BLK, 0, stream>>>(src, dst, buf0, nullptr, buf1, E);
        update_kernel<false, true><<<gN, BLK, 0, stream>>>(buf0, buf1, nullptr,
            convW1 + 0 * HF * HF, convb1 + 0 * HF, convW2 + 0 * HF * HF, convb2 + 0 * HF,
            buf1, N, stats);
        bn_finalize_kernel<<<1, 64, 0, stream>>>(stats, gamma + 0 * HF, beta + 0 * HF, ss0, invN, 1);

        hipMemsetAsync(buf0, 0, nh, stream);
        hipMemsetAsync(stats, 0, 32 * 4, stream);
        scatter_kernel<true><<<gE, BLK, 0, stream>>>(src, dst, buf1, ss0, buf0, E);
        update_kernel<true, true><<<gN, BLK, 0, stream>>>(buf1, buf0, ss0,
            convW1 + 1 * HF * HF, convb1 + 1 * HF, convW2 + 1 * HF * HF, convb2 + 1 * HF,
            buf0, N, stats);
        bn_finalize_kernel<<<1, 64, 0, stream>>>(stats, gamma + 1 * HF, beta + 1 * HF, ss1, invN, 1);

        hipMemsetAsync(buf1, 0, nh, stream);
        scatter_kernel<true><<<gE, BLK, 0, stream>>>(src, dst, buf0, ss1, buf1, E);
        update_kernel<true, false><<<gN, BLK, 0, stream>>>(buf0, buf1, ss1,
            convW1 + 2 * HF * HF, convb1 + 2 * HF, convW2 + 2 * HF * HF, convb2 + 2 * HF,
            buf1, N, nullptr);

        hipMemsetAsync(pool, 0, (size_t)G * (HF + 1) * sizeof(float), stream);
        pool_atomic_kernel<<<gN, BLK, 0, stream>>>(buf1, batch, pool, cnt, N);
        head_kernel<<<gG, BLK, 0, stream>>>(pool, cnt, postW1, postb1, postW2, postb2,
                                            (float*)d_out, G);
    }
}